// Round 6
// baseline (134.603 us; speedup 1.0000x reference)
//
#include <hip/hip_runtime.h>
#include <math.h>

constexpr int H  = 4096;
constexpr int H2 = 8192;

__device__ __forceinline__ float dot4s(const float4 w, const float4 v) {
    return fmaf(w.x, v.x, fmaf(w.y, v.y, fmaf(w.z, v.z, w.w * v.w)));
}

// One wave64 per (row, half): 8192 waves -> 2048 blocks -> 8 blocks/CU.
// Explicit register double-buffer: prefetch chunk it+1 while FMA-ing chunk it,
// so ~5-6 global_load_dwordx4 stay in flight per wave continuously (R5's
// VGPR=32 build waited vmcnt immediately -> issue stalls at chunk bounds).
// All prefetch temps statically named (no runtime-indexed arrays -> no scratch).
__global__ __launch_bounds__(256, 8)
void lstm_step_kernel(const float* __restrict__ h_prev,
                      const float* __restrict__ c_prev,
                      const float* __restrict__ x_t,
                      const float* __restrict__ W_f, const float* __restrict__ b_f,
                      const float* __restrict__ W_i, const float* __restrict__ b_i,
                      const float* __restrict__ W_C, const float* __restrict__ b_C,
                      const float* __restrict__ W_o, const float* __restrict__ b_o,
                      float* __restrict__ out)
{
    __shared__ float part[4][4];   // [wave][gate]

    const int wid  = threadIdx.x >> 6;          // 0..3
    const int lane = threadIdx.x & 63;
    const int row  = blockIdx.x * 2 + (wid >> 1);
    const int half = wid & 1;

    const size_t rowbase = (size_t)row * H2;
    const int hoff = half * 1024;               // float4 offset into the row
    const float4* wf = (const float4*)(W_f + rowbase) + hoff;
    const float4* wi = (const float4*)(W_i + rowbase) + hoff;
    const float4* wc = (const float4*)(W_C + rowbase) + hoff;
    const float4* wo = (const float4*)(W_o + rowbase) + hoff;
    const float4* hv = (const float4*)h_prev;
    const float4* xv = (const float4*)x_t;
    const float4* cv = (const float4*)c_prev;

    float sf = 0.f, si = 0.f, sc = 0.f, so = 0.f;

    if (half == 0) {
        // columns [0,H): z = h_prev for all four gates
        float4 z0 = hv[lane];
        float4 a0 = wf[lane];
        float4 b0 = wi[lane];
        float4 d0 = wc[lane];
        float4 e0 = wo[lane];
        for (int it = 0; it < 15; ++it) {
            const int c = (it + 1) * 64 + lane;
            const float4 z1 = hv[c];
            const float4 a1 = wf[c];
            const float4 b1 = wi[c];
            const float4 d1 = wc[c];
            const float4 e1 = wo[c];
            sf += dot4s(a0, z0);
            si += dot4s(b0, z0);
            sc += dot4s(d0, z0);
            so += dot4s(e0, z0);
            z0 = z1; a0 = a1; b0 = b1; d0 = d1; e0 = e1;
        }
        sf += dot4s(a0, z0);
        si += dot4s(b0, z0);
        sc += dot4s(d0, z0);
        so += dot4s(e0, z0);
    } else {
        // columns [H,2H): z = x_t for f,i,o ; z = c_prev for C
        float4 zx0 = xv[lane];
        float4 zc0 = cv[lane];
        float4 a0  = wf[lane];
        float4 b0  = wi[lane];
        float4 d0  = wc[lane];
        float4 e0  = wo[lane];
        for (int it = 0; it < 15; ++it) {
            const int c = (it + 1) * 64 + lane;
            const float4 zx1 = xv[c];
            const float4 zc1 = cv[c];
            const float4 a1  = wf[c];
            const float4 b1  = wi[c];
            const float4 d1  = wc[c];
            const float4 e1  = wo[c];
            sf += dot4s(a0, zx0);
            si += dot4s(b0, zx0);
            sc += dot4s(d0, zc0);
            so += dot4s(e0, zx0);
            zx0 = zx1; zc0 = zc1; a0 = a1; b0 = b1; d0 = d1; e0 = e1;
        }
        sf += dot4s(a0, zx0);
        si += dot4s(b0, zx0);
        sc += dot4s(d0, zc0);
        so += dot4s(e0, zx0);
    }

    #pragma unroll
    for (int off = 32; off > 0; off >>= 1) {
        sf += __shfl_down(sf, off, 64);
        si += __shfl_down(si, off, 64);
        sc += __shfl_down(sc, off, 64);
        so += __shfl_down(so, off, 64);
    }

    if (lane == 0) {
        part[wid][0] = sf;
        part[wid][1] = si;
        part[wid][2] = sc;
        part[wid][3] = so;
    }
    __syncthreads();

    if (threadIdx.x < 2) {
        const int r  = blockIdx.x * 2 + (int)threadIdx.x;
        const int w0 = (int)threadIdx.x * 2;
        const float tf = part[w0][0] + part[w0 + 1][0];
        const float ti = part[w0][1] + part[w0 + 1][1];
        const float tc = part[w0][2] + part[w0 + 1][2];
        const float to = part[w0][3] + part[w0 + 1][3];

        const float f      = 1.f / (1.f + expf(-(tf + b_f[r])));
        const float ig     = 1.f / (1.f + expf(-(ti + b_i[r])));
        const float ctilde = tanhf(tc + b_C[r]);
        const float og     = 1.f / (1.f + expf(-(to + b_o[r])));
        const float Cnew   = f * c_prev[r] + ig * ctilde;
        out[r]     = og * tanhf(Cnew);     // h_t
        out[H + r] = Cnew;                 // C_t
    }
}

extern "C" void kernel_launch(void* const* d_in, const int* in_sizes, int n_in,
                              void* d_out, int out_size, void* d_ws, size_t ws_size,
                              hipStream_t stream) {
    const float* h_prev = (const float*)d_in[0];
    const float* c_prev = (const float*)d_in[1];
    const float* x_t    = (const float*)d_in[2];
    const float* W_f    = (const float*)d_in[3];
    const float* b_f    = (const float*)d_in[4];
    const float* W_i    = (const float*)d_in[5];
    const float* b_i    = (const float*)d_in[6];
    const float* W_C    = (const float*)d_in[7];
    const float* b_C    = (const float*)d_in[8];
    const float* W_o    = (const float*)d_in[9];
    const float* b_o    = (const float*)d_in[10];
    float* out = (float*)d_out;

    // 2 rows per block (4 waves: row0-half0, row0-half1, row1-half0, row1-half1)
    lstm_step_kernel<<<H / 2, 256, 0, stream>>>(
        h_prev, c_prev, x_t, W_f, b_f, W_i, b_i, W_C, b_C, W_o, b_o, out);
}

// Round 7
// 95.406 us; speedup vs baseline: 1.4108x; 1.4108x over previous
//
#include <hip/hip_runtime.h>
#include <math.h>

constexpr int H  = 4096;
constexpr int H2 = 8192;

__device__ __forceinline__ float dot4s(const float4 w, const float4 v) {
    return fmaf(w.x, v.x, fmaf(w.y, v.y, fmaf(w.z, v.z, w.w * v.w)));
}

// One wave64 per full output row (R4 structure, best so far) + explicit
// register double-buffer (R6) under a 128-VGPR budget (launch_bounds 256,4).
// R6 spilled because (256,8)'s 64-VGPR cap can't hold 2x6 float4 of live
// prefetch state; here the live set (~85 VGPR) fits -> 5-6 loads in flight
// per wave with no scratch traffic.
__global__ __launch_bounds__(256, 4)
void lstm_step_kernel(const float* __restrict__ h_prev,
                      const float* __restrict__ c_prev,
                      const float* __restrict__ x_t,
                      const float* __restrict__ W_f, const float* __restrict__ b_f,
                      const float* __restrict__ W_i, const float* __restrict__ b_i,
                      const float* __restrict__ W_C, const float* __restrict__ b_C,
                      const float* __restrict__ W_o, const float* __restrict__ b_o,
                      float* __restrict__ out)
{
    const int gtid = blockIdx.x * blockDim.x + threadIdx.x;
    const int row  = gtid >> 6;
    const int lane = threadIdx.x & 63;
    if (row >= H) return;

    const float4* wf = (const float4*)(W_f + (size_t)row * H2);
    const float4* wi = (const float4*)(W_i + (size_t)row * H2);
    const float4* wc = (const float4*)(W_C + (size_t)row * H2);
    const float4* wo = (const float4*)(W_o + (size_t)row * H2);
    const float4* hv = (const float4*)h_prev;
    const float4* xv = (const float4*)x_t;
    const float4* cv = (const float4*)c_prev;

    float sf = 0.f, si = 0.f, sc = 0.f, so = 0.f;

    // ---- half 0: columns [0,H), z = h_prev for all four gates ----
    {
        float4 z0 = hv[lane];
        float4 a0 = wf[lane];
        float4 b0 = wi[lane];
        float4 d0 = wc[lane];
        float4 e0 = wo[lane];
        for (int it = 0; it < 15; ++it) {
            const int c = (it + 1) * 64 + lane;
            const float4 z1 = hv[c];
            const float4 a1 = wf[c];
            const float4 b1 = wi[c];
            const float4 d1 = wc[c];
            const float4 e1 = wo[c];
            sf += dot4s(a0, z0);
            si += dot4s(b0, z0);
            sc += dot4s(d0, z0);
            so += dot4s(e0, z0);
            z0 = z1; a0 = a1; b0 = b1; d0 = d1; e0 = e1;
        }
        sf += dot4s(a0, z0);
        si += dot4s(b0, z0);
        sc += dot4s(d0, z0);
        so += dot4s(e0, z0);
    }

    // ---- half 1: columns [H,2H), z = x_t for f,i,o ; z = c_prev for C ----
    {
        float4 zx0 = xv[lane];
        float4 zc0 = cv[lane];
        float4 a0  = wf[1024 + lane];
        float4 b0  = wi[1024 + lane];
        float4 d0  = wc[1024 + lane];
        float4 e0  = wo[1024 + lane];
        for (int it = 0; it < 15; ++it) {
            const int c = (it + 1) * 64 + lane;
            const int w = 1024 + c;
            const float4 zx1 = xv[c];
            const float4 zc1 = cv[c];
            const float4 a1  = wf[w];
            const float4 b1  = wi[w];
            const float4 d1  = wc[w];
            const float4 e1  = wo[w];
            sf += dot4s(a0, zx0);
            si += dot4s(b0, zx0);
            sc += dot4s(d0, zc0);
            so += dot4s(e0, zx0);
            zx0 = zx1; zc0 = zc1; a0 = a1; b0 = b1; d0 = d1; e0 = e1;
        }
        sf += dot4s(a0, zx0);
        si += dot4s(b0, zx0);
        sc += dot4s(d0, zc0);
        so += dot4s(e0, zx0);
    }

    #pragma unroll
    for (int off = 32; off > 0; off >>= 1) {
        sf += __shfl_down(sf, off, 64);
        si += __shfl_down(si, off, 64);
        sc += __shfl_down(sc, off, 64);
        so += __shfl_down(so, off, 64);
    }

    if (lane == 0) {
        const float f      = 1.f / (1.f + expf(-(sf + b_f[row])));
        const float ig     = 1.f / (1.f + expf(-(si + b_i[row])));
        const float ctilde = tanhf(sc + b_C[row]);
        const float og     = 1.f / (1.f + expf(-(so + b_o[row])));
        const float Cnew   = f * c_prev[row] + ig * ctilde;
        out[row]     = og * tanhf(Cnew);   // h_t
        out[H + row] = Cnew;               // C_t
    }
}

extern "C" void kernel_launch(void* const* d_in, const int* in_sizes, int n_in,
                              void* d_out, int out_size, void* d_ws, size_t ws_size,
                              hipStream_t stream) {
    const float* h_prev = (const float*)d_in[0];
    const float* c_prev = (const float*)d_in[1];
    const float* x_t    = (const float*)d_in[2];
    const float* W_f    = (const float*)d_in[3];
    const float* b_f    = (const float*)d_in[4];
    const float* W_i    = (const float*)d_in[5];
    const float* b_i    = (const float*)d_in[6];
    const float* W_C    = (const float*)d_in[7];
    const float* b_C    = (const float*)d_in[8];
    const float* W_o    = (const float*)d_in[9];
    const float* b_o    = (const float*)d_in[10];
    float* out = (float*)d_out;

    lstm_step_kernel<<<(H * 64) / 256, 256, 0, stream>>>(
        h_prev, c_prev, x_t, W_f, b_f, W_i, b_i, W_C, b_C, W_o, b_o, out);
}

// Round 8
// 81.317 us; speedup vs baseline: 1.6553x; 1.1733x over previous
//
#include <hip/hip_runtime.h>
#include <math.h>

constexpr int H  = 4096;
constexpr int H2 = 8192;

typedef float f32x4 __attribute__((ext_vector_type(4)));

__device__ __forceinline__ float dot4s(const f32x4 w, const f32x4 v) {
    return fmaf(w.x, v.x, fmaf(w.y, v.y, fmaf(w.z, v.z, w.w * v.w)));
}

// L3 partitioning: 512 MB of weights thrash the 256 MB Infinity Cache when
// all four matrices are cacheable (R1-R7: all variants pinned at ~95 us,
// 5.65 TB/s blended). Here W_f/W_C stay cacheable (256 MB -> L3-resident
// across graph replays) while W_i/W_o are read with nontemporal loads (nt
// flag: evict-first / no L3 allocate) so they stream from HBM without
// evicting the resident half. The two streams are served concurrently.
__global__ __launch_bounds__(256, 4)
void lstm_step_kernel(const float* __restrict__ h_prev,
                      const float* __restrict__ c_prev,
                      const float* __restrict__ x_t,
                      const float* __restrict__ W_f, const float* __restrict__ b_f,
                      const float* __restrict__ W_i, const float* __restrict__ b_i,
                      const float* __restrict__ W_C, const float* __restrict__ b_C,
                      const float* __restrict__ W_o, const float* __restrict__ b_o,
                      float* __restrict__ out)
{
    const int gtid = blockIdx.x * blockDim.x + threadIdx.x;
    const int row  = gtid >> 6;
    const int lane = threadIdx.x & 63;
    if (row >= H) return;

    const f32x4* wf = (const f32x4*)(W_f + (size_t)row * H2);
    const f32x4* wi = (const f32x4*)(W_i + (size_t)row * H2);
    const f32x4* wc = (const f32x4*)(W_C + (size_t)row * H2);
    const f32x4* wo = (const f32x4*)(W_o + (size_t)row * H2);
    const f32x4* hv = (const f32x4*)h_prev;
    const f32x4* xv = (const f32x4*)x_t;
    const f32x4* cv = (const f32x4*)c_prev;

    float sf = 0.f, si = 0.f, sc = 0.f, so = 0.f;

    // ---- half 0: columns [0,H), z = h_prev for all four gates ----
    for (int it = 0; it < 16; ++it) {
        const int c = it * 64 + lane;
        const f32x4 z = hv[c];
        const f32x4 a = wf[c];                              // cacheable
        const f32x4 b = __builtin_nontemporal_load(wi + c); // NT -> HBM stream
        const f32x4 d = wc[c];                              // cacheable
        const f32x4 e = __builtin_nontemporal_load(wo + c); // NT -> HBM stream
        sf += dot4s(a, z);
        si += dot4s(b, z);
        sc += dot4s(d, z);
        so += dot4s(e, z);
    }

    // ---- half 1: columns [H,2H), z = x_t for f,i,o ; z = c_prev for C ----
    for (int it = 0; it < 16; ++it) {
        const int c = it * 64 + lane;
        const int w = 1024 + c;
        const f32x4 zx = xv[c];
        const f32x4 zc = cv[c];
        const f32x4 a = wf[w];
        const f32x4 b = __builtin_nontemporal_load(wi + w);
        const f32x4 d = wc[w];
        const f32x4 e = __builtin_nontemporal_load(wo + w);
        sf += dot4s(a, zx);
        si += dot4s(b, zx);
        sc += dot4s(d, zc);
        so += dot4s(e, zx);
    }

    #pragma unroll
    for (int off = 32; off > 0; off >>= 1) {
        sf += __shfl_down(sf, off, 64);
        si += __shfl_down(si, off, 64);
        sc += __shfl_down(sc, off, 64);
        so += __shfl_down(so, off, 64);
    }

    if (lane == 0) {
        const float f      = 1.f / (1.f + expf(-(sf + b_f[row])));
        const float ig     = 1.f / (1.f + expf(-(si + b_i[row])));
        const float ctilde = tanhf(sc + b_C[row]);
        const float og     = 1.f / (1.f + expf(-(so + b_o[row])));
        const float Cnew   = f * c_prev[row] + ig * ctilde;
        out[row]     = og * tanhf(Cnew);   // h_t
        out[H + row] = Cnew;               // C_t
    }
}

extern "C" void kernel_launch(void* const* d_in, const int* in_sizes, int n_in,
                              void* d_out, int out_size, void* d_ws, size_t ws_size,
                              hipStream_t stream) {
    const float* h_prev = (const float*)d_in[0];
    const float* c_prev = (const float*)d_in[1];
    const float* x_t    = (const float*)d_in[2];
    const float* W_f    = (const float*)d_in[3];
    const float* b_f    = (const float*)d_in[4];
    const float* W_i    = (const float*)d_in[5];
    const float* b_i    = (const float*)d_in[6];
    const float* W_C    = (const float*)d_in[7];
    const float* b_C    = (const float*)d_in[8];
    const float* W_o    = (const float*)d_in[9];
    const float* b_o    = (const float*)d_in[10];
    float* out = (float*)d_out;

    lstm_step_kernel<<<(H * 64) / 256, 256, 0, stream>>>(
        h_prev, c_prev, x_t, W_f, b_f, W_i, b_i, W_C, b_C, W_o, b_o, out);
}